// Round 16
// baseline (803.971 us; speedup 1.0000x reference)
//
#include <hip/hip_runtime.h>

typedef unsigned short u16;
typedef unsigned int   u32;
typedef __attribute__((ext_vector_type(8))) short bf16x8;
typedef __attribute__((ext_vector_type(4))) float f32x4;

#define B_ROWS 32768
#define EPS_BN 1e-5f

// ---------- helpers ----------
__device__ __forceinline__ u16 f2bf(float f) {
  u32 u = __float_as_uint(f);
  u32 r = (u + 0x7FFFu + ((u >> 16) & 1u)) >> 16;   // RNE, no NaN inputs
  return (u16)r;
}
__device__ __forceinline__ float bf2f(u16 h) {
  return __uint_as_float(((u32)h) << 16);
}

// GENUINE numpy-fp32 emulation — contraction disabled (critical fix, R9)
__device__ __forceinline__ float dcalc(float px, float py, float sp, float mx, float my) {
#pragma clang fp contract(off)
  float sm   = mx * mx + my * my;
  float pm   = px * mx;
  float dot  = __builtin_fmaf(py, my, pm);
  float spsm = sp + sm;
  return spsm - 2.0f * dot;
}
__device__ __forceinline__ float dcalc2(float px, float py, float sp, float mx, float my,
                                        float sm) {
#pragma clang fp contract(off)
  float pm   = px * mx;
  float dot  = __builtin_fmaf(py, my, pm);
  float spsm = sp + sm;
  return spsm - 2.0f * dot;
}
__device__ __forceinline__ float smcalc(float mx, float my) {
#pragma clang fp contract(off)
  return mx * mx + my * my;
}
__device__ __forceinline__ float spcalc(float px, float py) {
#pragma clang fp contract(off)
  return px * px + py * py;
}
#define MED3 __builtin_amdgcn_fmed3f

// ---------- KNN: 32 queries/block, 8 queries/thread x 128-pt slice (R13, proven) ------
__global__ __launch_bounds__(256, 4)
void knn_kernel(const float2* __restrict__ pos, const float2* __restrict__ mc,
                const float2* __restrict__ mv, float* __restrict__ knn_out,
                u16* __restrict__ X0)
{
  __shared__ float tv[32 * 130];
  __shared__ float tstS[32];
  __shared__ int   qcnt[32];

  const int t = threadIdx.x;
  const int g = t >> 6;
  const int s = t & 63;
  const int q0 = blockIdx.x * 32;

  float px[8], py[8], sp[8];
#pragma unroll
  for (int j = 0; j < 8; ++j) {
    float2 p = pos[q0 + g * 8 + j];
    px[j] = p.x; py[j] = p.y; sp[j] = spcalc(p.x, p.y);
  }

  const float4* mc4 = (const float4*)mc;
  const int b4 = s * 64;
  const int basePt = s * 128;

  float z0[8], z1[8];
#pragma unroll
  for (int j = 0; j < 8; ++j) { z0[j] = __builtin_inff(); z1[j] = __builtin_inff(); }

  float4 cur = mc4[b4];
  for (int i = 0; i < 64; ++i) {
    float4 nxt = mc4[b4 + ((i + 1) & 63)];
    float smA = smcalc(cur.x, cur.y);
    float smB = smcalc(cur.z, cur.w);
#pragma unroll
    for (int j = 0; j < 8; ++j) {
      float dA = dcalc2(px[j], py[j], sp[j], cur.x, cur.y, smA);
      z1[j] = MED3(z0[j], dA, z1[j]); z0[j] = fminf(z0[j], dA);
      float dB = dcalc2(px[j], py[j], sp[j], cur.z, cur.w, smB);
      z1[j] = MED3(z0[j], dB, z1[j]); z0[j] = fminf(z0[j], dB);
    }
    cur = nxt;
  }
#pragma unroll
  for (int j = 0; j < 8; ++j) {
    tv[(g * 8 + j) * 130 + s * 2 + 0] = z0[j];
    tv[(g * 8 + j) * 130 + s * 2 + 1] = z1[j];
  }
  __syncthreads();

  if (t < 32) {
    float ch[16];
#pragma unroll
    for (int j = 0; j < 16; ++j) ch[j] = __builtin_inff();
    for (int k = 0; k < 128; ++k) {
      float v = tv[t * 130 + k];
#pragma unroll
      for (int j = 15; j >= 1; --j) ch[j] = MED3(ch[j-1], v, ch[j]);
      ch[0] = fminf(ch[0], v);
    }
    tstS[t] = ch[15];
    qcnt[t] = 0;
  }
  __syncthreads();
  float Tq[8];
#pragma unroll
  for (int j = 0; j < 8; ++j) Tq[j] = tstS[g * 8 + j];
  __syncthreads();

  u16* qcand = (u16*)tv;
  for (int i = 0; i < 64; ++i) {
    float4 c2 = mc4[b4 + i];
    float smA = smcalc(c2.x, c2.y);
    float smB = smcalc(c2.z, c2.w);
    const int idxA = basePt + 2 * i;
#pragma unroll
    for (int j = 0; j < 8; ++j) {
      float dA = dcalc2(px[j], py[j], sp[j], c2.x, c2.y, smA);
      if (dA <= Tq[j]) {
        int o = atomicAdd(&qcnt[g * 8 + j], 1);
        if (o < 64) qcand[(g * 8 + j) * 64 + o] = (u16)idxA;
      }
      float dB = dcalc2(px[j], py[j], sp[j], c2.z, c2.w, smB);
      if (dB <= Tq[j]) {
        int o = atomicAdd(&qcnt[g * 8 + j], 1);
        if (o < 64) qcand[(g * 8 + j) * 64 + o] = (u16)(idxA + 1);
      }
    }
  }
  __syncthreads();

  if (t < 32) {
    const int q = q0 + t;
    float2 p = pos[q];
    const float sq = spcalc(p.x, p.y);
    int cnt = qcnt[t]; if (cnt > 64) cnt = 64;
    float fd[16]; int fi[16];
#pragma unroll
    for (int j = 0; j < 16; ++j) { fd[j] = __builtin_inff(); fi[j] = 0x7fffffff; }
    for (int j = 0; j < cnt; ++j) {
      int ci = qcand[t * 64 + j];
      float2 m = mc[ci];
      float d = dcalc(p.x, p.y, sq, m.x, m.y);
      bool cc = (d < fd[15]) || (d == fd[15] && ci < fi[15]);
      if (cc) {
#pragma unroll
        for (int k = 15; k >= 1; --k) {
          bool cm = (d < fd[k-1]) || (d == fd[k-1] && ci < fi[k-1]);
          if (cc) {
            if (cm) { fd[k] = fd[k-1]; fi[k] = fi[k-1]; }
            else    { fd[k] = d;       fi[k] = ci;      }
          }
          cc = cm;
        }
        if (cc) { fd[0] = d; fi[0] = ci; }
      }
    }
    float* orow = knn_out + (size_t)q * 66;
    u16*   xrow = X0 + (size_t)q * 96;
    orow[0] = p.x; orow[1] = p.y;
    xrow[0] = f2bf(p.x); xrow[1] = f2bf(p.y);
#pragma unroll
    for (int j = 0; j < 16; ++j) {
      int ci = fi[j];
      float2 m = mc[ci], v = mv[ci];
      orow[2 + 4*j + 0] = m.x; orow[2 + 4*j + 1] = m.y;
      orow[2 + 4*j + 2] = v.x; orow[2 + 4*j + 3] = v.y;
      xrow[2 + 4*j + 0] = f2bf(m.x); xrow[2 + 4*j + 1] = f2bf(m.y);
      xrow[2 + 4*j + 2] = f2bf(v.x); xrow[2 + 4*j + 3] = f2bf(v.y);
    }
#pragma unroll
    for (int c = 66; c < 96; ++c) xrow[c] = 0;
  }
}

// ---------- persistent MLP (single kernel, manual grid barrier) ----------
struct MlpArgs {
  const u16* X0;
  u16 *ZA, *ZB;
  u16 *WT1, *WT2, *WT3, *WT4, *WT5;
  const float *w1,*b1,*w2,*b2,*w3,*b3,*w4,*b4,*w5,*b5,*w6,*b6;
  const float *g1,*be1,*g2,*be2,*g3,*be3,*g4,*be4,*g5,*be5;
  float* stats;
  int*   bar;       // [0]=arrive counter, [1]=release sense (pre-zeroed via memsetAsync)
  float* outX;
};

#define MLP_GRID 512

// sense-reversing grid barrier; all MLP_GRID blocks guaranteed co-resident
// (launch_bounds(256,2) => 2 blocks/CU capacity => 512 == capacity).
__device__ __forceinline__ void grid_barrier(int* bar, int& sense)
{
  __syncthreads();
  if (threadIdx.x == 0) {
    ++sense;
    __threadfence();                                   // release prior writes
    if (atomicAdd(&bar[0], 1) == MLP_GRID - 1) {
      atomicExch(&bar[0], 0);                          // reset for next barrier
      __threadfence();
      atomicExch(&bar[1], sense);                      // release all
    } else {
      while (atomicAdd(&bar[1], 0) < sense) { __builtin_amdgcn_s_sleep(2); }
    }
    __threadfence();                                   // acquire
  }
  __syncthreads();
}

// phase 0: WT prep (fp32 [K][N] -> bf16 [N][Kpad]) + zero stats
__device__ void prep_phase(const MlpArgs& a)
{
  const int gid  = blockIdx.x * 256 + threadIdx.x;
  const int nthr = MLP_GRID * 256;
  if (gid < 2176) a.stats[gid] = 0.0f;
  for (int i = gid; i < 249856; i += nthr) {
    int r = i; const float* w; u16* wt; int N, K, Kp;
    if (r < 12288)                 { w = a.w1; wt = a.WT1; N = 128; K = 66;  Kp = 96;  }
    else if ((r -= 12288) < 32768) { w = a.w2; wt = a.WT2; N = 256; K = 128; Kp = 128; }
    else if ((r -= 32768) < 131072){ w = a.w3; wt = a.WT3; N = 512; K = 256; Kp = 256; }
    else if ((r -= 131072) < 65536){ w = a.w4; wt = a.WT4; N = 128; K = 512; Kp = 512; }
    else { r -= 65536;               w = a.w5; wt = a.WT5; N = 64;  K = 128; Kp = 128; }
    int n = r / Kp, kp = r - n * Kp;
    float v = (kp < K) ? w[(size_t)kp * N + n] : 0.0f;
    wt[r] = f2bf(v);
  }
}

// GEMM tile phase (bf16 MFMA, BM=128 x BN) + bias + column stats
template<int BN>
__device__ void gemm_phase(const u16* __restrict__ X, int Kw,
                           const u16* __restrict__ WT, const float* __restrict__ bias,
                           u16* __restrict__ Z, int N,
                           float* csum, float* csq, char* smem)
{
  constexpr int AST = 40;
  u16*   Ash  = (u16*)smem;                    // 10240 B
  u16*   Bsh  = (u16*)(smem + 10240);          // <=10240 B
  float* redS = (float*)(smem + 20480);        // <=2048 B
  float* redQ = (float*)(smem + 22528);        // <=2048 B

  const int t = threadIdx.x;
  const int wave = t >> 6;
  const int lane = t & 63;
  const int lr = lane & 15;
  const int qd = lane >> 4;
  const int sr = t >> 2;
  const int sk = (t & 3) * 8;

  const int nTiles = 256 * (N / BN);
  for (int tile = blockIdx.x; tile < nTiles; tile += MLP_GRID) {
    const int m0 = (tile & 255) * 128;
    const int n0 = (tile >> 8) * BN;

    f32x4 acc[2][BN / 16];
#pragma unroll
    for (int aa = 0; aa < 2; ++aa)
#pragma unroll
      for (int bb = 0; bb < BN / 16; ++bb) {
        acc[aa][bb][0] = 0.f; acc[aa][bb][1] = 0.f;
        acc[aa][bb][2] = 0.f; acc[aa][bb][3] = 0.f;
      }

    for (int k0 = 0; k0 < Kw; k0 += 32) {
#pragma unroll
      for (int rr = 0; rr < 2; ++rr) {
        int r = sr + rr * 64;
        *(uint4*)(&Ash[r * AST + sk]) =
            *(const uint4*)(&X[(size_t)(m0 + r) * Kw + k0 + sk]);
      }
      if (BN == 128) {
#pragma unroll
        for (int rr = 0; rr < 2; ++rr) {
          int n = sr + rr * 64;
          *(uint4*)(&Bsh[n * AST + sk]) =
              *(const uint4*)(&WT[(size_t)(n0 + n) * Kw + k0 + sk]);
        }
      } else {
        int n = sr;
        *(uint4*)(&Bsh[n * AST + sk]) =
            *(const uint4*)(&WT[(size_t)(n0 + n) * Kw + k0 + sk]);
      }
      __syncthreads();
      bf16x8 af0 = *(const bf16x8*)(&Ash[(wave * 32 + lr) * AST + qd * 8]);
      bf16x8 af1 = *(const bf16x8*)(&Ash[(wave * 32 + 16 + lr) * AST + qd * 8]);
#pragma unroll
      for (int ct = 0; ct < BN / 16; ++ct) {
        bf16x8 bfr = *(const bf16x8*)(&Bsh[(ct * 16 + lr) * AST + qd * 8]);
        acc[0][ct] = __builtin_amdgcn_mfma_f32_16x16x32_bf16(af0, bfr, acc[0][ct], 0, 0, 0);
        acc[1][ct] = __builtin_amdgcn_mfma_f32_16x16x32_bf16(af1, bfr, acc[1][ct], 0, 0, 0);
      }
      __syncthreads();
    }

    // epilogue: bias, bf16 Z store, per-column partial sums
#pragma unroll
    for (int ct = 0; ct < BN / 16; ++ct) {
      int cg = n0 + ct * 16 + lr;
      float bv = bias[cg];
      float s = 0.f, sqv = 0.f;
#pragma unroll
      for (int rt = 0; rt < 2; ++rt) {
#pragma unroll
        for (int r = 0; r < 4; ++r) {
          float z = acc[rt][ct][r] + bv;
          int row = m0 + wave * 32 + rt * 16 + qd * 4 + r;  // C/D: row=quad*4+reg
          Z[(size_t)row * N + cg] = f2bf(z);
          s += z;
          sqv = __fmaf_rn(z, z, sqv);
        }
      }
      s   += __shfl_xor(s, 16);   s   += __shfl_xor(s, 32);
      sqv += __shfl_xor(sqv, 16); sqv += __shfl_xor(sqv, 32);
      if (qd == 0) { redS[wave * BN + ct * 16 + lr] = s; redQ[wave * BN + ct * 16 + lr] = sqv; }
    }
    __syncthreads();
    if (t < BN) {
      float s = 0.f, sv = 0.f;
#pragma unroll
      for (int gg = 0; gg < 4; ++gg) { s += redS[gg * BN + t]; sv += redQ[gg * BN + t]; }
      atomicAdd(&csum[n0 + t], s);
      atomicAdd(&csq[n0 + t], sv);
    }
    __syncthreads();
  }
}

// BN+ReLU apply, in-place on Z (bit-identical op sequence to R14 FUSE path)
__device__ void apply_phase(u16* Z, int N, const float* psum, const float* psq,
                            const float* gw, const float* bw, char* smem)
{
  float* sc = (float*)smem;
  float* tt = (float*)(smem + 2048);
  const int t = threadIdx.x;
  const float invB = 1.0f / 32768.0f;
  for (int c = t; c < N; c += 256) {
    float mean = psum[c] * invB;
    float var  = __fmaf_rn(-mean, mean, psq[c] * invB);
    float s    = gw[c] * rsqrtf(var + EPS_BN);
    sc[c] = s;
    tt[c] = __fmaf_rn(-mean, s, bw[c]);
  }
  __syncthreads();
  const int total8 = 32768 * (N / 8);
  for (int i8 = blockIdx.x * 256 + t; i8 < total8; i8 += MLP_GRID * 256) {
    uint4 zp = ((const uint4*)Z)[i8];
    const int c0 = (i8 * 8) & (N - 1);
    u32 wv[4] = {zp.x, zp.y, zp.z, zp.w};
    u32 ov[4];
#pragma unroll
    for (int u = 0; u < 4; ++u) {
      u32 res = 0;
#pragma unroll
      for (int hl = 0; hl < 2; ++hl) {
        int c = c0 + 2 * u + hl;
        float zz = bf2f((u16)((wv[u] >> (16 * hl)) & 0xffffu));
        float y  = fmaxf(__fmaf_rn(zz, sc[c], tt[c]), 0.0f);
        res |= ((u32)f2bf(y)) << (16 * hl);
      }
      ov[u] = res;
    }
    uint4 o4; o4.x = ov[0]; o4.y = ov[1]; o4.z = ov[2]; o4.w = ov[3];
    ((uint4*)Z)[i8] = o4;
  }
  __syncthreads();
}

// final: fused BN5+ReLU + 64->2 GEMV, fp32 out
__device__ void gemv_phase(const u16* Z5, const float* w6, const float* b6,
                           const float* psum, const float* psq,
                           const float* gw, const float* bw, float* out, char* smem)
{
  float* wsh = (float*)smem;            // 128 f
  float* scs = (float*)(smem + 512);    // 64 f
  float* tts = (float*)(smem + 768);    // 64 f
  const int t = threadIdx.x;
  if (t < 128) wsh[t] = w6[t];
  if (t < 64) {
    const float invB = 1.0f / 32768.0f;
    float mean = psum[t] * invB;
    float var  = __fmaf_rn(-mean, mean, psq[t] * invB);
    float sc   = gw[t] * rsqrtf(var + EPS_BN);
    scs[t] = sc;
    tts[t] = __fmaf_rn(-mean, sc, bw[t]);
  }
  __syncthreads();
  for (int q = blockIdx.x * 256 + t; q < 32768; q += MLP_GRID * 256) {
    const uint4* xv = (const uint4*)(Z5 + (size_t)q * 64);
    float a0 = 0.f, a1 = 0.f;
#pragma unroll
    for (int cc = 0; cc < 8; ++cc) {
      uint4 pk = xv[cc];
      u32 u[4] = {pk.x, pk.y, pk.z, pk.w};
#pragma unroll
      for (int uu = 0; uu < 4; ++uu) {
        int k = cc * 8 + uu * 2;
        float z0 = bf2f((u16)(u[uu] & 0xffffu));
        float z1 = bf2f((u16)(u[uu] >> 16));
        float x0 = fmaxf(__fmaf_rn(z0, scs[k],     tts[k]),     0.0f);
        float x1 = fmaxf(__fmaf_rn(z1, scs[k + 1], tts[k + 1]), 0.0f);
        x0 = bf2f(f2bf(x0));  // match prior bf16 round-trip of activations
        x1 = bf2f(f2bf(x1));
        a0 = __fmaf_rn(x0, wsh[2 * k + 0], a0);
        a1 = __fmaf_rn(x0, wsh[2 * k + 1], a1);
        a0 = __fmaf_rn(x1, wsh[2 * k + 2], a0);
        a1 = __fmaf_rn(x1, wsh[2 * k + 3], a1);
      }
    }
    float2 o; o.x = a0 + b6[0]; o.y = a1 + b6[1];
    ((float2*)out)[q] = o;
  }
}

__global__ __launch_bounds__(256, 2)
void mlp_kernel(MlpArgs a)
{
  __shared__ __align__(16) char smem[24576];
  int sense = 0;
  int* bar = a.bar;

  float* s1 = a.stats;        float* s2 = a.stats + 128;  float* s3 = a.stats + 384;
  float* s4 = a.stats + 896;  float* s5 = a.stats + 1024;
  float* sqb = a.stats + 1088;
  float* q1 = sqb;            float* q2 = sqb + 128;      float* q3 = sqb + 384;
  float* q4 = sqb + 896;      float* q5 = sqb + 1024;

  prep_phase(a);
  grid_barrier(bar, sense);
  gemm_phase<64> (a.X0, 96,  a.WT1, a.b1, a.ZA, 128, s1, q1, smem);
  grid_barrier(bar, sense);
  apply_phase(a.ZA, 128, s1, q1, a.g1, a.be1, smem);
  grid_barrier(bar, sense);
  gemm_phase<128>(a.ZA, 128, a.WT2, a.b2, a.ZB, 256, s2, q2, smem);
  grid_barrier(bar, sense);
  apply_phase(a.ZB, 256, s2, q2, a.g2, a.be2, smem);
  grid_barrier(bar, sense);
  gemm_phase<128>(a.ZB, 256, a.WT3, a.b3, a.ZA, 512, s3, q3, smem);
  grid_barrier(bar, sense);
  apply_phase(a.ZA, 512, s3, q3, a.g3, a.be3, smem);
  grid_barrier(bar, sense);
  gemm_phase<64> (a.ZA, 512, a.WT4, a.b4, a.ZB, 128, s4, q4, smem);
  grid_barrier(bar, sense);
  apply_phase(a.ZB, 128, s4, q4, a.g4, a.be4, smem);
  grid_barrier(bar, sense);
  gemm_phase<64> (a.ZB, 128, a.WT5, a.b5, a.ZA, 64, s5, q5, smem);
  grid_barrier(bar, sense);
  gemv_phase(a.ZA, a.w6, a.b6, s5, q5, a.g5, a.be5, a.outX, smem);
}

// ---------- launch ----------
extern "C" void kernel_launch(void* const* d_in, const int* in_sizes, int n_in,
                              void* d_out, int out_size, void* d_ws, size_t ws_size,
                              hipStream_t stream)
{
  const float2* pos = (const float2*)d_in[0];
  const float2* mc  = (const float2*)d_in[1];
  const float2* mv  = (const float2*)d_in[2];

  // ws layout (bf16): X0 6.29MB | ZA 33.55MB | ZB 33.55MB | WT1..5 | stats | bar
  char* ws = (char*)d_ws;
  u16* X0   = (u16*)(ws + 0);
  u16* ZA   = (u16*)(ws + 6291456);
  u16* ZB   = (u16*)(ws + 39845888);
  u16* WT1  = (u16*)(ws + 73400320);
  u16* WT2  = (u16*)(ws + 73424896);
  u16* WT3  = (u16*)(ws + 73490432);
  u16* WT4  = (u16*)(ws + 73752576);
  u16* WT5  = (u16*)(ws + 73883648);
  float* stats = (float*)(ws + 73900032);
  int*   bar   = (int*)(ws + 73908736);   // 2 ints, pre-zeroed below

  float* outX = (float*)d_out;
  float* outK = outX + 2 * B_ROWS;

  hipMemsetAsync(bar, 0, 2 * sizeof(int), stream);
  knn_kernel<<<dim3(1024), 256, 0, stream>>>(pos, mc, mv, outK, X0);

  MlpArgs a;
  a.X0 = X0; a.ZA = ZA; a.ZB = ZB;
  a.WT1 = WT1; a.WT2 = WT2; a.WT3 = WT3; a.WT4 = WT4; a.WT5 = WT5;
  a.w1 = (const float*)d_in[3];  a.b1 = (const float*)d_in[4];
  a.w2 = (const float*)d_in[5];  a.b2 = (const float*)d_in[6];
  a.w3 = (const float*)d_in[7];  a.b3 = (const float*)d_in[8];
  a.w4 = (const float*)d_in[9];  a.b4 = (const float*)d_in[10];
  a.w5 = (const float*)d_in[11]; a.b5 = (const float*)d_in[12];
  a.w6 = (const float*)d_in[13]; a.b6 = (const float*)d_in[14];
  a.g1 = (const float*)d_in[15]; a.be1 = (const float*)d_in[16];
  a.g2 = (const float*)d_in[17]; a.be2 = (const float*)d_in[18];
  a.g3 = (const float*)d_in[19]; a.be3 = (const float*)d_in[20];
  a.g4 = (const float*)d_in[21]; a.be4 = (const float*)d_in[22];
  a.g5 = (const float*)d_in[23]; a.be5 = (const float*)d_in[24];
  a.stats = stats; a.bar = bar; a.outX = outX;

  mlp_kernel<<<dim3(MLP_GRID), dim3(256), 0, stream>>>(a);

  (void)in_sizes; (void)n_in; (void)out_size; (void)ws_size;
}